// Round 3
// baseline (52060.950 us; speedup 1.0000x reference)
//
#include <hip/hip_runtime.h>
#include <math.h>

// GRUDetector: B=1024, T=512, F=64, H=128, gates (r,z,n), + MLP head (H->32->1).
// R3: R1/R2 failed because the compiler DEMOTED the per-thread weight arrays to
// scratch (R2: VGPR=84 < 96 floats needed; 62 GB refetch + 52 GB spill traffic).
// Fix: 24 NAMED float4 registers per thread (no arrays -> demotion impossible).
// Mapping: thread (g = tid>>1, half = tid&1); 768 thr = 12 waves = 3/SIMD.
// Half-combine via DPP quad_perm add (VALU) instead of shfl (DS pipe).
// All LDS reads are 2-address broadcasts (free) or stride-1.

#define Bsz  1024
#define Tlen 512
#define Fdim 64
#define Hdim 128
#define Gdim 384
#define GPAD 385
#define NB   4
#define NTHR 768

__device__ __forceinline__ float pair_sum(float v) {
    // add lane^1 partner via DPP quad_perm(1,0,3,2) = 0xB1 (pure VALU op)
    int t = __builtin_amdgcn_update_dpp(0, __float_as_int(v), 0xB1, 0xF, 0xF, true);
    return v + __int_as_float(t);
}
__device__ __forceinline__ float fast_sigmoid(float v) {
    return __builtin_amdgcn_rcpf(1.f + __expf(-v));
}
__device__ __forceinline__ float fast_tanh(float v) {
    // 1 - 2/(e^{2v}+1): saturates correctly at +-inf
    return 1.f - 2.f * __builtin_amdgcn_rcpf(__expf(2.f * v) + 1.f);
}

__global__ __launch_bounds__(NTHR, 3)
void gru_persist(const float* __restrict__ x,
                 const float* __restrict__ W_ih, const float* __restrict__ W_hh,
                 const float* __restrict__ b_ih, const float* __restrict__ b_hh,
                 const float* __restrict__ W1, const float* __restrict__ b1,
                 const float* __restrict__ W2, const float* __restrict__ b2,
                 float* __restrict__ out)
{
    __shared__ float h_lds[NB][Hdim];      // 2 KB
    __shared__ float x_lds[NB][Fdim];      // 1 KB
    __shared__ float xg_lds[NB][GPAD];     // 6 KB (padded: gate writes hit 32 banks)
    __shared__ float hg_lds[NB][GPAD];     // 6 KB
    __shared__ float hid_lds[NB][32];

    const int tid  = threadIdx.x;
    const int g    = tid >> 1;             // gate row 0..383
    const int half = tid & 1;
    const int b0   = blockIdx.x * NB;
    const int hoff = half * (Hdim / 2);    // 0 or 64
    const int xoff = half * (Fdim / 2);    // 0 or 32

    // ---- one-time: half weight rows -> 24 NAMED float4 registers (96 fp32)
    const float4* pa = reinterpret_cast<const float4*>(W_ih + (size_t)g * Fdim + xoff);
    const float4* pb = reinterpret_cast<const float4*>(W_hh + (size_t)g * Hdim + hoff);
    float4 wa0=pa[0], wa1=pa[1], wa2=pa[2], wa3=pa[3];
    float4 wa4=pa[4], wa5=pa[5], wa6=pa[6], wa7=pa[7];
    float4 wb0 =pb[0],  wb1 =pb[1],  wb2 =pb[2],  wb3 =pb[3];
    float4 wb4 =pb[4],  wb5 =pb[5],  wb6 =pb[6],  wb7 =pb[7];
    float4 wb8 =pb[8],  wb9 =pb[9],  wb10=pb[10], wb11=pb[11];
    float4 wb12=pb[12], wb13=pb[13], wb14=pb[14], wb15=pb[15];

    const float bi = half ? 0.f : b_ih[g];  // bias contributed by half 0 only
    const float bh = half ? 0.f : b_hh[g];

    // ---- init h = 0 and stage x(t=0)
    for (int i = tid; i < NB * Hdim; i += NTHR) h_lds[i >> 7][i & 127] = 0.f;
    if (tid < NB * Fdim) {
        int b = tid >> 6, j = tid & 63;
        x_lds[b][j] = x[((size_t)(b0 + b) * Tlen) * Fdim + j];
    }
    __syncthreads();

#define HSTEP(i, bb, ACC) { float4 v_ = *reinterpret_cast<const float4*>(&h_lds[bb][hoff + 4*(i)]); \
    ACC = fmaf(wb##i.x, v_.x, ACC); ACC = fmaf(wb##i.y, v_.y, ACC); \
    ACC = fmaf(wb##i.z, v_.z, ACC); ACC = fmaf(wb##i.w, v_.w, ACC); }
#define XSTEP(i, bb, ACC) { float4 v_ = *reinterpret_cast<const float4*>(&x_lds[bb][xoff + 4*(i)]); \
    ACC = fmaf(wa##i.x, v_.x, ACC); ACC = fmaf(wa##i.y, v_.y, ACC); \
    ACC = fmaf(wa##i.z, v_.z, ACC); ACC = fmaf(wa##i.w, v_.w, ACC); }
#define DOT_ALL(bb, HACC, XACC) \
    HSTEP(0,bb,HACC)  HSTEP(1,bb,HACC)  HSTEP(2,bb,HACC)  HSTEP(3,bb,HACC)  \
    HSTEP(4,bb,HACC)  HSTEP(5,bb,HACC)  HSTEP(6,bb,HACC)  HSTEP(7,bb,HACC)  \
    HSTEP(8,bb,HACC)  HSTEP(9,bb,HACC)  HSTEP(10,bb,HACC) HSTEP(11,bb,HACC) \
    HSTEP(12,bb,HACC) HSTEP(13,bb,HACC) HSTEP(14,bb,HACC) HSTEP(15,bb,HACC) \
    XSTEP(0,bb,XACC)  XSTEP(1,bb,XACC)  XSTEP(2,bb,XACC)  XSTEP(3,bb,XACC)  \
    XSTEP(4,bb,XACC)  XSTEP(5,bb,XACC)  XSTEP(6,bb,XACC)  XSTEP(7,bb,XACC)

    for (int t = 0; t < Tlen; ++t) {
        // ---- issue x(t+1) prefetch early (threads 512..767)
        float xpref = 0.f;
        if (tid >= 512 && t + 1 < Tlen) {
            int i = tid - 512, b = i >> 6, j = i & 63;
            xpref = x[((size_t)(b0 + b) * Tlen + (t + 1)) * Fdim + j];
        }

        // ---- GEMV: 4 named accumulator chains per side (ILP), static unroll
        float ha0=bh, ha1=bh, ha2=bh, ha3=bh;
        float xa0=bi, xa1=bi, xa2=bi, xa3=bi;
        DOT_ALL(0, ha0, xa0)
        DOT_ALL(1, ha1, xa1)
        DOT_ALL(2, ha2, xa2)
        DOT_ALL(3, ha3, xa3)

        // combine halves (DPP pair add); half0 writes xg, half1 writes hg
        float s;
        s = pair_sum(xa0); if (half == 0) xg_lds[0][g] = s;
        s = pair_sum(xa1); if (half == 0) xg_lds[1][g] = s;
        s = pair_sum(xa2); if (half == 0) xg_lds[2][g] = s;
        s = pair_sum(xa3); if (half == 0) xg_lds[3][g] = s;
        s = pair_sum(ha0); if (half == 1) hg_lds[0][g] = s;
        s = pair_sum(ha1); if (half == 1) hg_lds[1][g] = s;
        s = pair_sum(ha2); if (half == 1) hg_lds[2][g] = s;
        s = pair_sum(ha3); if (half == 1) hg_lds[3][g] = s;
        __syncthreads();

        // ---- gates (threads 0..511) ; x(t+1) write-back (threads 512..767)
        if (tid < NB * Hdim) {
            int b = tid >> 7, k = tid & 127;
            float xr = xg_lds[b][k],            hr = hg_lds[b][k];
            float xz = xg_lds[b][Hdim + k],     hz = hg_lds[b][Hdim + k];
            float xn = xg_lds[b][2*Hdim + k],   hn = hg_lds[b][2*Hdim + k];
            float r = fast_sigmoid(xr + hr);
            float z = fast_sigmoid(xz + hz);
            float n = fast_tanh(xn + r * hn);
            h_lds[b][k] = (1.f - z) * n + z * h_lds[b][k];
        } else if (t + 1 < Tlen) {
            int i = tid - 512, b = i >> 6, j = i & 63;
            x_lds[b][j] = xpref;
        }
        __syncthreads();
    }

    // ---- epilogue MLP: hidden = relu(h @ W1.T + b1); out = hidden @ W2.T + b2
    if (tid < NB * 32) {
        int b = tid >> 5, u = tid & 31;
        float a = b1[u];
        #pragma unroll
        for (int k = 0; k < Hdim; ++k) a += W1[u * Hdim + k] * h_lds[b][k];
        hid_lds[b][u] = fmaxf(a, 0.f);
    }
    __syncthreads();
    if (tid < NB) {
        float a = b2[0];
        #pragma unroll
        for (int u = 0; u < 32; ++u) a += W2[u] * hid_lds[tid][u];
        out[b0 + tid] = a;
    }
}

extern "C" void kernel_launch(void* const* d_in, const int* in_sizes, int n_in,
                              void* d_out, int out_size, void* d_ws, size_t ws_size,
                              hipStream_t stream)
{
    const float* x    = (const float*)d_in[0];
    const float* W_ih = (const float*)d_in[1];
    const float* W_hh = (const float*)d_in[2];
    const float* b_ih = (const float*)d_in[3];
    const float* b_hh = (const float*)d_in[4];
    const float* W1   = (const float*)d_in[5];
    const float* b1   = (const float*)d_in[6];
    const float* W2   = (const float*)d_in[7];
    const float* b2   = (const float*)d_in[8];
    float* out = (float*)d_out;

    dim3 grid(Bsz / NB), block(NTHR);
    hipLaunchKernelGGL(gru_persist, grid, block, 0, stream,
                       x, W_ih, W_hh, b_ih, b_hh, W1, b1, W2, b2, out);
}